// Round 1
// baseline (293.615 us; speedup 1.0000x reference)
//
#include <hip/hip_runtime.h>

typedef unsigned short u16;
typedef unsigned int u32;
typedef short bf16x8 __attribute__((ext_vector_type(8)));
typedef float f32x4 __attribute__((ext_vector_type(4)));

#define DEVINL __device__ __forceinline__

DEVINL u16 f2bf(float f) {
    u32 u = __builtin_bit_cast(u32, f);
    u32 r = u + 0x7fffu + ((u >> 16) & 1u);   // RNE
    return (u16)(r >> 16);
}

// ---------------------------------------------------------------- cast x -> bf16
__global__ __launch_bounds__(256) void cast_x_kernel(const float4* __restrict__ in,
                                                     u16* __restrict__ outp) {
    int i = blockIdx.x * 256 + threadIdx.x;   // grid covers 4096*1024/4 exactly
    float4 v = in[i];
    ushort4 o;
    o.x = f2bf(v.x); o.y = f2bf(v.y); o.z = f2bf(v.z); o.w = f2bf(v.w);
    *(ushort4*)&outp[(size_t)i * 4] = o;
}

// ------------------------------------------ transpose+cast weights: W[K][N] -> Wt[N][K] bf16
__global__ __launch_bounds__(256) void transpose_cast(
    const float* __restrict__ W0, const float* __restrict__ W1,
    const float* __restrict__ W2, const float* __restrict__ W3,
    u16* __restrict__ T0, u16* __restrict__ T1,
    u16* __restrict__ T2, u16* __restrict__ T3) {
    __shared__ __align__(16) u16 lds[64 * 68];
    int bid = blockIdx.x;
    const float* W; u16* T;
    switch (bid >> 8) {
        case 0:  W = W0; T = T0; break;
        case 1:  W = W1; T = T1; break;
        case 2:  W = W2; T = T2; break;
        default: W = W3; T = T3; break;
    }
    int tile = bid & 255;
    int k0 = (tile >> 4) << 6;
    int n0 = (tile & 15) << 6;
    int t = threadIdx.x;
    int rk = t >> 2;            // 0..63 (k row)
    int cb = (t & 3) << 4;      // 0,16,32,48 (n chunk)
#pragma unroll
    for (int j = 0; j < 4; ++j) {
        float4 v = *(const float4*)&W[(size_t)(k0 + rk) * 1024 + n0 + cb + 4 * j];
        ushort4 o;
        o.x = f2bf(v.x); o.y = f2bf(v.y); o.z = f2bf(v.z); o.w = f2bf(v.w);
        *(ushort4*)&lds[rk * 68 + cb + 4 * j] = o;
    }
    __syncthreads();
    int rn = t >> 2;            // output n row
#pragma unroll
    for (int j2 = 0; j2 < 2; ++j2) {
        u16 tmp[8];
#pragma unroll
        for (int u = 0; u < 8; ++u)
            tmp[u] = lds[(cb + 8 * j2 + u) * 68 + rn];
        *(uint4*)&T[(size_t)(n0 + rn) * 1024 + k0 + cb + 8 * j2] = *(uint4*)tmp;
    }
}

// ---------------------------------------------------------------- GEMM (m97-style 128^2 tile)
// MODE 0: C[4096,3072] = xb @ [Wq|Wk|Wv]^T-stored, +bias, write Q/K/V bf16 [B,H,S,64]
// MODE 1: C[4096,1024] = Ob @ Wo^T-stored, +bo, write fp32 d_out
template <int MODE>
__global__ __launch_bounds__(256) void gemm_kernel(
    const u16* __restrict__ A,
    const u16* __restrict__ W0t, const u16* __restrict__ W1t, const u16* __restrict__ W2t,
    const float* __restrict__ b0, const float* __restrict__ b1, const float* __restrict__ b2,
    u16* __restrict__ Oq, u16* __restrict__ Ok, u16* __restrict__ Ov,
    float* __restrict__ Fout) {
    constexpr int NB = (MODE == 0) ? 24 : 8;
    const int mb = blockIdx.x / NB, nb = blockIdx.x % NB;
    const int m0 = mb * 128, n0 = nb * 128;
    const int tid = threadIdx.x, lane = tid & 63, w = tid >> 6;
    const int wr = w >> 1, wc = w & 1;
    const int c = lane & 15, g = lane >> 4;

    __shared__ __align__(16) u16 Alds[128 * 64];
    __shared__ __align__(16) u16 Blds[128 * 64];

    const u16* Wt; const float* bias; int ncol0;
    if (MODE == 0) {
        const int tsel = n0 >> 10;
        Wt   = (tsel == 0) ? W0t : ((tsel == 1) ? W1t : W2t);
        bias = (tsel == 0) ? b0  : ((tsel == 1) ? b1  : b2);
        ncol0 = n0 & 1023;
    } else {
        Wt = W0t; bias = b0; ncol0 = n0;
    }

    const u16* Asrc = A  + (size_t)(m0    + 32 * w + (lane >> 3)) * 1024 + (lane & 7) * 8;
    const u16* Bsrc = Wt + (size_t)(ncol0 + 32 * w + (lane >> 3)) * 1024 + (lane & 7) * 8;
    u16* AldsW = &Alds[(32 * w) * 64];
    u16* BldsW = &Blds[(32 * w) * 64];

    f32x4 acc[4][4] = {};

    for (int kt = 0; kt < 16; ++kt) {
        const int k0 = kt * 64;
#pragma unroll
        for (int i = 0; i < 4; ++i) {
            __builtin_amdgcn_global_load_lds(
                (const __attribute__((address_space(1))) void*)(Asrc + k0 + i * 8 * 1024),
                (__attribute__((address_space(3))) void*)(AldsW + i * 8 * 64), 16, 0, 0);
            __builtin_amdgcn_global_load_lds(
                (const __attribute__((address_space(1))) void*)(Bsrc + k0 + i * 8 * 1024),
                (__attribute__((address_space(3))) void*)(BldsW + i * 8 * 64), 16, 0, 0);
        }
        __syncthreads();
#pragma unroll
        for (int kk = 0; kk < 2; ++kk) {
            bf16x8 af[4], bfr[4];
#pragma unroll
            for (int mf = 0; mf < 4; ++mf)
                af[mf] = *(const bf16x8*)&Alds[(c + 16 * mf + 64 * wr) * 64 + 8 * g + 32 * kk];
#pragma unroll
            for (int nf = 0; nf < 4; ++nf)
                bfr[nf] = *(const bf16x8*)&Blds[(c + 16 * nf + 64 * wc) * 64 + 8 * g + 32 * kk];
#pragma unroll
            for (int mf = 0; mf < 4; ++mf)
#pragma unroll
                for (int nf = 0; nf < 4; ++nf)
                    acc[mf][nf] = __builtin_amdgcn_mfma_f32_16x16x32_bf16(
                        af[mf], bfr[nf], acc[mf][nf], 0, 0, 0);
        }
        __syncthreads();
    }

    float biasv[4];
#pragma unroll
    for (int nf = 0; nf < 4; ++nf) biasv[nf] = bias[ncol0 + 64 * wc + 16 * nf + c];

    if (MODE == 0) {
        const int bi = m0 >> 11;
        const int tsel = n0 >> 10;
        u16* Odst = (tsel == 0) ? Oq : ((tsel == 1) ? Ok : Ov);
#pragma unroll
        for (int nf = 0; nf < 4; ++nf) {
            const int n_in = ncol0 + 64 * wc + 16 * nf + c;   // [0,1024) within tensor
            const int h = n_in >> 6, d = n_in & 63;
            u16* base = Odst + ((size_t)(bi * 16 + h)) * 2048 * 64 + d;
#pragma unroll
            for (int mf = 0; mf < 4; ++mf)
#pragma unroll
                for (int r = 0; r < 4; ++r) {
                    const int m = m0 + 64 * wr + 16 * mf + 4 * g + r;
                    const int s = m & 2047;
                    base[(size_t)s * 64] = f2bf(acc[mf][nf][r] + biasv[nf]);
                }
        }
    } else {
#pragma unroll
        for (int mf = 0; mf < 4; ++mf)
#pragma unroll
            for (int r = 0; r < 4; ++r) {
                const int m = m0 + 64 * wr + 16 * mf + 4 * g + r;
                float* rowp = Fout + (size_t)m * 1024 + n0 + 64 * wc;
#pragma unroll
                for (int nf = 0; nf < 4; ++nf)
                    rowp[16 * nf + c] = acc[mf][nf][r] + biasv[nf];
            }
    }
}

// ---------------------------------------------------------------- flash attention
// grid: B*H*(S/64) blocks, 256 thr (4 waves); wave owns 16 q-rows; 64-key tiles.
__global__ __launch_bounds__(256) void attn_kernel(
    const u16* __restrict__ Q, const u16* __restrict__ K, const u16* __restrict__ V,
    u16* __restrict__ O) {
    const int bid = blockIdx.x;
    const int qb = bid & 31, h = (bid >> 5) & 15, b = bid >> 9;
    const int tid = threadIdx.x, lane = tid & 63, w = tid >> 6;
    const int c = lane & 15, g = lane >> 4;

    __shared__ __align__(16) u16 Klds[64 * 72];    // [key][dim], pad 8
    __shared__ __align__(16) u16 Vtlds[64 * 72];   // [dim][key], pad 8
    __shared__ __align__(16) u16 Plds[4][16 * 72]; // per-wave [q][key]

    const size_t headoff = ((size_t)(b * 16 + h)) * 2048 * 64;
    const u16* Qh = Q + headoff;
    const u16* Kh = K + headoff;
    const u16* Vh = V + headoff;

    // Q frags in registers (A-operand: row = lane&15, k contiguous per 16-lane group)
    const int sq = qb * 64 + w * 16 + c;
    bf16x8 qf[2];
    qf[0] = *(const bf16x8*)&Qh[(size_t)sq * 64 + 8 * g];
    qf[1] = *(const bf16x8*)&Qh[(size_t)sq * 64 + 32 + 8 * g];

    f32x4 oacc[4] = {};
    float mrun[4], lrun[4];
#pragma unroll
    for (int r = 0; r < 4; ++r) { mrun[r] = -1e30f; lrun[r] = 0.f; }

    const int krow = tid >> 3;          // 0..31
    const int kcol8 = (tid & 7) * 8;    // dim chunk
    const int vkp = tid >> 3;           // key pair 0..31
    const int vd8 = (tid & 7) * 8;      // dim chunk

    for (int kt = 0; kt < 32; ++kt) {
        const u16* Ktile = Kh + (size_t)(kt * 64) * 64;
        const u16* Vtile = Vh + (size_t)(kt * 64) * 64;
        // stage K row-major [64][72]
        uint4 ka = *(const uint4*)&Ktile[(size_t)krow * 64 + kcol8];
        uint4 kb2 = *(const uint4*)&Ktile[(size_t)(krow + 32) * 64 + kcol8];
        *(uint4*)&Klds[krow * 72 + kcol8] = ka;
        *(uint4*)&Klds[(krow + 32) * 72 + kcol8] = kb2;
        // stage V transposed [dim][key]
        uint4 va = *(const uint4*)&Vtile[(size_t)(2 * vkp) * 64 + vd8];
        uint4 vb = *(const uint4*)&Vtile[(size_t)(2 * vkp + 1) * 64 + vd8];
        const u16* pa = (const u16*)&va;
        const u16* pb = (const u16*)&vb;
#pragma unroll
        for (int j = 0; j < 8; ++j) {
            u32 pack = (u32)pa[j] | ((u32)pb[j] << 16);
            *(u32*)&Vtlds[(vd8 + j) * 72 + 2 * vkp] = pack;
        }
        __syncthreads();

        // S = Q K^T  (A=Q rows, B=K^T: col=key, k=dim)
        f32x4 sacc[4] = {};
#pragma unroll
        for (int kk = 0; kk < 2; ++kk) {
#pragma unroll
            for (int ct = 0; ct < 4; ++ct) {
                bf16x8 kf = *(const bf16x8*)&Klds[(c + 16 * ct) * 72 + 8 * g + 32 * kk];
                sacc[ct] = __builtin_amdgcn_mfma_f32_16x16x32_bf16(qf[kk], kf, sacc[ct], 0, 0, 0);
            }
        }
        // online softmax (rows 4g+r live in the 16 lanes of group g)
        float alpha[4];
#pragma unroll
        for (int r = 0; r < 4; ++r) {
            float mx = fmaxf(fmaxf(sacc[0][r], sacc[1][r]), fmaxf(sacc[2][r], sacc[3][r]));
            mx *= 0.125f;
#pragma unroll
            for (int sft = 1; sft < 16; sft <<= 1) mx = fmaxf(mx, __shfl_xor(mx, sft, 64));
            float mnew = fmaxf(mrun[r], mx);
            alpha[r] = __expf(mrun[r] - mnew);
            mrun[r] = mnew;
        }
        u16 pv16[4][4];
        float rsum[4] = {0.f, 0.f, 0.f, 0.f};
#pragma unroll
        for (int ct = 0; ct < 4; ++ct)
#pragma unroll
            for (int r = 0; r < 4; ++r) {
                float p = __expf(sacc[ct][r] * 0.125f - mrun[r]);
                rsum[r] += p;
                pv16[ct][r] = f2bf(p);
            }
#pragma unroll
        for (int r = 0; r < 4; ++r) {
            float s = rsum[r];
#pragma unroll
            for (int sft = 1; sft < 16; sft <<= 1) s += __shfl_xor(s, sft, 64);
            lrun[r] = lrun[r] * alpha[r] + s;
        }
        // P -> wave-private LDS (re-layout C-frag -> A-frag)
#pragma unroll
        for (int ct = 0; ct < 4; ++ct)
#pragma unroll
            for (int r = 0; r < 4; ++r)
                Plds[w][(4 * g + r) * 72 + c + 16 * ct] = pv16[ct][r];
        __syncthreads();
        // rescale O
#pragma unroll
        for (int ct = 0; ct < 4; ++ct)
#pragma unroll
            for (int r = 0; r < 4; ++r) oacc[ct][r] *= alpha[r];
        // O += P V   (A=P: row=q, k=key; B=V: k=key, col=dim -> Vt rows)
#pragma unroll
        for (int kk = 0; kk < 2; ++kk) {
            bf16x8 pf = *(const bf16x8*)&Plds[w][c * 72 + 8 * g + 32 * kk];
#pragma unroll
            for (int ct = 0; ct < 4; ++ct) {
                bf16x8 vf = *(const bf16x8*)&Vtlds[(c + 16 * ct) * 72 + 8 * g + 32 * kk];
                oacc[ct] = __builtin_amdgcn_mfma_f32_16x16x32_bf16(pf, vf, oacc[ct], 0, 0, 0);
            }
        }
        __syncthreads();
    }
    // finalize: O /= l, write bf16 [B,S,H*64]
    const int srow_base = qb * 64 + w * 16;
    const size_t obase = ((size_t)(b * 2048 + srow_base)) * 1024 + h * 64;
#pragma unroll
    for (int ct = 0; ct < 4; ++ct)
#pragma unroll
        for (int r = 0; r < 4; ++r) {
            float val = oacc[ct][r] / lrun[r];
            O[obase + (size_t)(4 * g + r) * 1024 + c + 16 * ct] = f2bf(val);
        }
}

// ---------------------------------------------------------------- launch
extern "C" void kernel_launch(void* const* d_in, const int* in_sizes, int n_in,
                              void* d_out, int out_size, void* d_ws, size_t ws_size,
                              hipStream_t stream) {
    const float* x  = (const float*)d_in[0];
    const float* Wq = (const float*)d_in[1];
    const float* bq = (const float*)d_in[2];
    const float* Wk = (const float*)d_in[3];
    const float* bk = (const float*)d_in[4];
    const float* Wv = (const float*)d_in[5];
    const float* bv = (const float*)d_in[6];
    const float* Wo = (const float*)d_in[7];
    const float* bo = (const float*)d_in[8];
    float* out = (float*)d_out;

    if (ws_size < (size_t)51 * 1024 * 1024) return;  // need 48 MB scratch

    u16* ws  = (u16*)d_ws;
    u16* xb  = ws;                       // 4096*1024
    u16* wqt = xb  + 4096 * 1024;        // 1024*1024 each, transposed [N][K]
    u16* wkt = wqt + 1024 * 1024;
    u16* wvt = wkt + 1024 * 1024;
    u16* wot = wvt + 1024 * 1024;
    u16* Qb  = wot + 1024 * 1024;        // [2][16][2048][64]
    u16* Kb  = Qb + 4194304;
    u16* Vb  = Kb + 4194304;
    u16* Ob  = Vb + 4194304;             // [4096][1024]

    cast_x_kernel<<<4096, 256, 0, stream>>>((const float4*)x, xb);
    transpose_cast<<<1024, 256, 0, stream>>>(Wq, Wk, Wv, Wo, wqt, wkt, wvt, wot);
    gemm_kernel<0><<<768, 256, 0, stream>>>(xb, wqt, wkt, wvt, bq, bk, bv,
                                            Qb, Kb, Vb, nullptr);
    attn_kernel<<<1024, 256, 0, stream>>>(Qb, Kb, Vb, Ob);
    gemm_kernel<1><<<256, 256, 0, stream>>>(Ob, wot, nullptr, nullptr, bo, nullptr, nullptr,
                                            nullptr, nullptr, nullptr, out);
}

// Round 4
// 239.618 us; speedup vs baseline: 1.2253x; 1.2253x over previous
//
#include <hip/hip_runtime.h>

typedef unsigned short u16;
typedef unsigned int u32;
typedef short bf16x4 __attribute__((ext_vector_type(4)));
typedef short bf16x8 __attribute__((ext_vector_type(8)));
typedef float f32x4 __attribute__((ext_vector_type(4)));
typedef u32 u32x2 __attribute__((ext_vector_type(2)));
typedef u32 u32x4 __attribute__((ext_vector_type(4)));

#define DEVINL __device__ __forceinline__

DEVINL u16 f2bf(float f) {
    u32 u = __builtin_bit_cast(u32, f);
    u32 r = u + 0x7fffu + ((u >> 16) & 1u);   // RNE
    return (u16)(r >> 16);
}

DEVINL u32 pack2(float a, float b) {          // bf16(a) | bf16(b)<<16
    return (u32)f2bf(a) | ((u32)f2bf(b) << 16);
}

// ---------------------------------------------------------------- cast x -> bf16
__global__ __launch_bounds__(256) void cast_x_kernel(const float4* __restrict__ in,
                                                     u16* __restrict__ outp) {
    int i = blockIdx.x * 256 + threadIdx.x;
    float4 v = in[i];
    ushort4 o;
    o.x = f2bf(v.x); o.y = f2bf(v.y); o.z = f2bf(v.z); o.w = f2bf(v.w);
    *(ushort4*)&outp[(size_t)i * 4] = o;
}

// ------------------------------------------ transpose+cast weights: W[K][N] -> Wt[N][K] bf16
__global__ __launch_bounds__(256) void transpose_cast(
    const float* __restrict__ W0, const float* __restrict__ W1,
    const float* __restrict__ W2, const float* __restrict__ W3,
    u16* __restrict__ T0, u16* __restrict__ T1,
    u16* __restrict__ T2, u16* __restrict__ T3) {
    __shared__ __align__(16) u16 lds[64 * 68];
    int bid = blockIdx.x;
    const float* W; u16* T;
    switch (bid >> 8) {
        case 0:  W = W0; T = T0; break;
        case 1:  W = W1; T = T1; break;
        case 2:  W = W2; T = T2; break;
        default: W = W3; T = T3; break;
    }
    int tile = bid & 255;
    int k0 = (tile >> 4) << 6;
    int n0 = (tile & 15) << 6;
    int t = threadIdx.x;
    int rk = t >> 2;
    int cb = (t & 3) << 4;
#pragma unroll
    for (int j = 0; j < 4; ++j) {
        float4 v = *(const float4*)&W[(size_t)(k0 + rk) * 1024 + n0 + cb + 4 * j];
        ushort4 o;
        o.x = f2bf(v.x); o.y = f2bf(v.y); o.z = f2bf(v.z); o.w = f2bf(v.w);
        *(ushort4*)&lds[rk * 68 + cb + 4 * j] = o;
    }
    __syncthreads();
    int rn = t >> 2;
#pragma unroll
    for (int j2 = 0; j2 < 2; ++j2) {
        u16 tmp[8];
#pragma unroll
        for (int u = 0; u < 8; ++u)
            tmp[u] = lds[(cb + 8 * j2 + u) * 68 + rn];
        *(uint4*)&T[(size_t)(n0 + rn) * 1024 + k0 + cb + 8 * j2] = *(uint4*)tmp;
    }
}

// ---------------------------------------------------------------- GEMM (m97-style 128^2 tile)
// MODE 0: C[4096,3072] = xb @ [Wq|Wk|Wv]^T-stored, +bias; Q,K -> [B,H,S,64]; V -> [B,H,64,S]
// MODE 1: C[4096,1024] = Ob @ Wo^T-stored, +bo, write fp32 d_out
template <int MODE>
__global__ __launch_bounds__(256) void gemm_kernel(
    const u16* __restrict__ A,
    const u16* __restrict__ W0t, const u16* __restrict__ W1t, const u16* __restrict__ W2t,
    const float* __restrict__ b0, const float* __restrict__ b1, const float* __restrict__ b2,
    u16* __restrict__ Oq, u16* __restrict__ Ok, u16* __restrict__ Ov,
    float* __restrict__ Fout) {
    constexpr int NB = (MODE == 0) ? 24 : 8;
    const int mb = blockIdx.x / NB, nb = blockIdx.x % NB;
    const int m0 = mb * 128, n0 = nb * 128;
    const int tid = threadIdx.x, lane = tid & 63, w = tid >> 6;
    const int wr = w >> 1, wc = w & 1;
    const int c = lane & 15, g = lane >> 4;

    __shared__ __align__(16) u16 Alds[128 * 64];
    __shared__ __align__(16) u16 Blds[128 * 64];

    const u16* Wt; const float* bias; int ncol0;
    if (MODE == 0) {
        const int tsel = n0 >> 10;
        Wt   = (tsel == 0) ? W0t : ((tsel == 1) ? W1t : W2t);
        bias = (tsel == 0) ? b0  : ((tsel == 1) ? b1  : b2);
        ncol0 = n0 & 1023;
    } else {
        Wt = W0t; bias = b0; ncol0 = n0;
    }

    const u16* Asrc = A  + (size_t)(m0    + 32 * w + (lane >> 3)) * 1024 + (lane & 7) * 8;
    const u16* Bsrc = Wt + (size_t)(ncol0 + 32 * w + (lane >> 3)) * 1024 + (lane & 7) * 8;
    u16* AldsW = &Alds[(32 * w) * 64];
    u16* BldsW = &Blds[(32 * w) * 64];

    f32x4 acc[4][4] = {};

    for (int kt = 0; kt < 16; ++kt) {
        const int k0 = kt * 64;
#pragma unroll
        for (int i = 0; i < 4; ++i) {
            __builtin_amdgcn_global_load_lds(
                (const __attribute__((address_space(1))) void*)(Asrc + k0 + i * 8 * 1024),
                (__attribute__((address_space(3))) void*)(AldsW + i * 8 * 64), 16, 0, 0);
            __builtin_amdgcn_global_load_lds(
                (const __attribute__((address_space(1))) void*)(Bsrc + k0 + i * 8 * 1024),
                (__attribute__((address_space(3))) void*)(BldsW + i * 8 * 64), 16, 0, 0);
        }
        __syncthreads();
#pragma unroll
        for (int kk = 0; kk < 2; ++kk) {
            bf16x8 af[4], bfr[4];
#pragma unroll
            for (int mf = 0; mf < 4; ++mf)
                af[mf] = *(const bf16x8*)&Alds[(c + 16 * mf + 64 * wr) * 64 + 8 * g + 32 * kk];
#pragma unroll
            for (int nf = 0; nf < 4; ++nf)
                bfr[nf] = *(const bf16x8*)&Blds[(c + 16 * nf + 64 * wc) * 64 + 8 * g + 32 * kk];
#pragma unroll
            for (int mf = 0; mf < 4; ++mf)
#pragma unroll
                for (int nf = 0; nf < 4; ++nf)
                    acc[mf][nf] = __builtin_amdgcn_mfma_f32_16x16x32_bf16(
                        af[mf], bfr[nf], acc[mf][nf], 0, 0, 0);
        }
        __syncthreads();
    }

    float biasv[4];
#pragma unroll
    for (int nf = 0; nf < 4; ++nf) biasv[nf] = bias[ncol0 + 64 * wc + 16 * nf + c];

    if (MODE == 0) {
        const int bi = m0 >> 11;
        const int tsel = n0 >> 10;
        if (tsel < 2) {
            u16* Odst = (tsel == 0) ? Oq : Ok;
#pragma unroll
            for (int nf = 0; nf < 4; ++nf) {
                const int n_in = ncol0 + 64 * wc + 16 * nf + c;
                const int h = n_in >> 6, d = n_in & 63;
                u16* base = Odst + ((size_t)(bi * 16 + h)) * 2048 * 64 + d;
#pragma unroll
                for (int mf = 0; mf < 4; ++mf)
#pragma unroll
                    for (int r = 0; r < 4; ++r) {
                        const int m = m0 + 64 * wr + 16 * mf + 4 * g + r;
                        const int s = m & 2047;
                        base[(size_t)s * 64] = f2bf(acc[mf][nf][r] + biasv[nf]);
                    }
            }
        } else {
            // V transposed: Vt[((bi*16+h)*64 + d)*2048 + s]; 4 consecutive s per (mf,nf)
#pragma unroll
            for (int nf = 0; nf < 4; ++nf) {
                const int n_in = ncol0 + 64 * wc + 16 * nf + c;
                const int h = n_in >> 6, d = n_in & 63;
                u16* base = Ov + ((size_t)((bi * 16 + h) * 64 + d)) * 2048;
#pragma unroll
                for (int mf = 0; mf < 4; ++mf) {
                    const int s = (m0 & 2047) + 64 * wr + 16 * mf + 4 * g;
                    u32x2 pr = {pack2(acc[mf][nf][0] + biasv[nf], acc[mf][nf][1] + biasv[nf]),
                                pack2(acc[mf][nf][2] + biasv[nf], acc[mf][nf][3] + biasv[nf])};
                    *(u32x2*)&base[s] = pr;
                }
            }
        }
    } else {
#pragma unroll
        for (int mf = 0; mf < 4; ++mf)
#pragma unroll
            for (int r = 0; r < 4; ++r) {
                const int m = m0 + 64 * wr + 16 * mf + 4 * g + r;
                float* rowp = Fout + (size_t)m * 1024 + n0 + 64 * wc;
#pragma unroll
                for (int nf = 0; nf < 4; ++nf)
                    rowp[16 * nf + c] = acc[mf][nf][r] + biasv[nf];
            }
    }
}

// ---------------------------------------------------------------- flash attention
// Swapped-operand, 16x16x32 only (all layouts HW-verified in-problem).
// grid: 512 = B(2) x H(16) x (2048/128); 4 waves; wave owns 32 q (2 q-tiles of 16).
// Per 64-key tile:
//   S[key][q] via A=K,B=Q (4 key-tiles x 2 q-tiles x 2 K-halves = 16 MFMA).
//   Lane (c,g) holds S[16T+4g+r][q=c] -> softmax reduce over g via shfl_xor(16,32).
//   PV with claimed k-map kappa(g,j) = 32kb + (j<4 ? 4g+j : 16+4g+j-4):
//   B-frag = lane's own packed P words (zero shuffles), A-frag = matching V cols.
__global__ __launch_bounds__(256) void attn_kernel(
    const u16* __restrict__ Q, const u16* __restrict__ K, const u16* __restrict__ Vt,
    u16* __restrict__ O) {
    const int bid0 = blockIdx.x;
    const int bid = (bid0 & 7) * 64 + (bid0 >> 3);   // XCD-chunked swizzle (512 % 8 == 0)
    const int qb = bid & 15, h = (bid >> 4) & 15, b = bid >> 8;
    const int tid = threadIdx.x, lane = tid & 63, w = tid >> 6;
    const int c = lane & 15, g = lane >> 4;

    __shared__ __align__(16) u16 Klds[2][64 * 72];   // [key][dim]
    __shared__ __align__(16) u16 Vlds[2][64 * 72];   // [dim][key]

    const size_t hoff = ((size_t)(b * 16 + h)) * 2048 * 64;
    const u16* Qh = Q + hoff;
    const u16* Kh = K + hoff;
    const u16* Vh = Vt + hoff;      // [64 dims][2048 keys]

    const int qw = qb * 128 + w * 32;     // wave's q base
    bf16x8 qf[2][2];
#pragma unroll
    for (int u = 0; u < 2; ++u)
#pragma unroll
        for (int kk = 0; kk < 2; ++kk)
            qf[u][kk] = *(const bf16x8*)&Qh[(size_t)(qw + 16 * u + c) * 64 + 8 * g + 32 * kk];

    f32x4 oacc[4][2] = {};                // [dim-tile][q-tile]
    float mrun[2] = {-3.0e38f, -3.0e38f}, lrun[2] = {0.f, 0.f};

    const int srow = tid >> 3;            // 0..31
    const int scol = (tid & 7) * 8;

    {   // prologue: stage tile 0 into buffer 0
        uint4 ka = *(const uint4*)&Kh[(size_t)srow * 64 + scol];
        uint4 kb2 = *(const uint4*)&Kh[(size_t)(srow + 32) * 64 + scol];
        uint4 va = *(const uint4*)&Vh[(size_t)srow * 2048 + scol];
        uint4 vb = *(const uint4*)&Vh[(size_t)(srow + 32) * 2048 + scol];
        *(uint4*)&Klds[0][srow * 72 + scol] = ka;
        *(uint4*)&Klds[0][(srow + 32) * 72 + scol] = kb2;
        *(uint4*)&Vlds[0][srow * 72 + scol] = va;
        *(uint4*)&Vlds[0][(srow + 32) * 72 + scol] = vb;
    }
    __syncthreads();

    for (int kt = 0; kt < 32; ++kt) {
        const int cur = kt & 1, nxt = cur ^ 1;
        uint4 ka, kb2, va, vb;
        if (kt < 31) {
            ka  = *(const uint4*)&Kh[(size_t)((kt + 1) * 64 + srow) * 64 + scol];
            kb2 = *(const uint4*)&Kh[(size_t)((kt + 1) * 64 + srow + 32) * 64 + scol];
            va  = *(const uint4*)&Vh[(size_t)srow * 2048 + (kt + 1) * 64 + scol];
            vb  = *(const uint4*)&Vh[(size_t)(srow + 32) * 2048 + (kt + 1) * 64 + scol];
        }
        const u16* Kb0 = &Klds[cur][0];
        const u16* Vb0 = &Vlds[cur][0];

        // S[key][q]: sacc[T][u], lane holds rows 4g+r of key-tile T, col q=c
        f32x4 sacc[4][2] = {};
#pragma unroll
        for (int T = 0; T < 4; ++T)
#pragma unroll
            for (int kk = 0; kk < 2; ++kk) {
                bf16x8 kf = *(const bf16x8*)&Kb0[(16 * T + c) * 72 + 8 * g + 32 * kk];
#pragma unroll
                for (int u = 0; u < 2; ++u)
                    sacc[T][u] = __builtin_amdgcn_mfma_f32_16x16x32_bf16(
                        kf, qf[u][kk], sacc[T][u], 0, 0, 0);
            }

        // online softmax per q-tile (reduce over g-groups: lanes {c,c+16,c+32,c+48})
        float alpha[2];
#pragma unroll
        for (int u = 0; u < 2; ++u) {
            float mx = sacc[0][u][0];
#pragma unroll
            for (int T = 0; T < 4; ++T)
#pragma unroll
                for (int r = 0; r < 4; ++r) mx = fmaxf(mx, sacc[T][u][r]);
            mx = fmaxf(mx, __shfl_xor(mx, 16));
            mx = fmaxf(mx, __shfl_xor(mx, 32));
            const float mnew = fmaxf(mrun[u], mx * 0.125f);
            alpha[u] = __expf(mrun[u] - mnew);
            mrun[u] = mnew;
        }

        // P = exp(S*scale - m); pack pairs; row-sums
        u32 pw[4][2][2];                  // [T][u][pair]: keys (16T+4g+2p, +1)
        float lsum[2] = {0.f, 0.f};
#pragma unroll
        for (int T = 0; T < 4; ++T)
#pragma unroll
            for (int u = 0; u < 2; ++u) {
                float p0 = __expf(sacc[T][u][0] * 0.125f - mrun[u]);
                float p1 = __expf(sacc[T][u][1] * 0.125f - mrun[u]);
                float p2 = __expf(sacc[T][u][2] * 0.125f - mrun[u]);
                float p3 = __expf(sacc[T][u][3] * 0.125f - mrun[u]);
                lsum[u] += (p0 + p1) + (p2 + p3);
                pw[T][u][0] = pack2(p0, p1);
                pw[T][u][1] = pack2(p2, p3);
            }
#pragma unroll
        for (int u = 0; u < 2; ++u) {
            float s = lsum[u];
            s += __shfl_xor(s, 16);
            s += __shfl_xor(s, 32);
            lrun[u] = lrun[u] * alpha[u] + s;
#pragma unroll
            for (int dt = 0; dt < 4; ++dt)
#pragma unroll
                for (int r = 0; r < 4; ++r) oacc[dt][u][r] *= alpha[u];
        }

        // PV: O[dim][q] += V^T . P^T over 2 key-blocks of 32, claimed-map kappa
#pragma unroll
        for (int kb = 0; kb < 2; ++kb) {
            bf16x8 pf[2];
#pragma unroll
            for (int u = 0; u < 2; ++u) {
                u32x4 ww = {pw[2 * kb][u][0], pw[2 * kb][u][1],
                            pw[2 * kb + 1][u][0], pw[2 * kb + 1][u][1]};
                pf[u] = __builtin_bit_cast(bf16x8, ww);
            }
#pragma unroll
            for (int dt = 0; dt < 4; ++dt) {
                bf16x4 v0 = *(const bf16x4*)&Vb0[(16 * dt + c) * 72 + 32 * kb + 4 * g];
                bf16x4 v1 = *(const bf16x4*)&Vb0[(16 * dt + c) * 72 + 32 * kb + 16 + 4 * g];
                bf16x8 vf = __builtin_shufflevector(v0, v1, 0, 1, 2, 3, 4, 5, 6, 7);
#pragma unroll
                for (int u = 0; u < 2; ++u)
                    oacc[dt][u] = __builtin_amdgcn_mfma_f32_16x16x32_bf16(
                        vf, pf[u], oacc[dt][u], 0, 0, 0);
            }
        }

        if (kt < 31) {
            *(uint4*)&Klds[nxt][srow * 72 + scol] = ka;
            *(uint4*)&Klds[nxt][(srow + 32) * 72 + scol] = kb2;
            *(uint4*)&Vlds[nxt][srow * 72 + scol] = va;
            *(uint4*)&Vlds[nxt][(srow + 32) * 72 + scol] = vb;
        }
        __syncthreads();
    }

    // epilogue: O[b, s=q, h*64 + dim], dim = 16*dt + 4g + r, q = qw + 16u + c
#pragma unroll
    for (int u = 0; u < 2; ++u) {
        const float inv = 1.0f / lrun[u];
        const size_t obase = ((size_t)(b * 2048 + qw + 16 * u + c)) * 1024 + h * 64 + 4 * g;
#pragma unroll
        for (int dt = 0; dt < 4; ++dt) {
            u32x2 pr = {pack2(oacc[dt][u][0] * inv, oacc[dt][u][1] * inv),
                        pack2(oacc[dt][u][2] * inv, oacc[dt][u][3] * inv)};
            *(u32x2*)&O[obase + 16 * dt] = pr;
        }
    }
}

// ---------------------------------------------------------------- launch
extern "C" void kernel_launch(void* const* d_in, const int* in_sizes, int n_in,
                              void* d_out, int out_size, void* d_ws, size_t ws_size,
                              hipStream_t stream) {
    const float* x  = (const float*)d_in[0];
    const float* Wq = (const float*)d_in[1];
    const float* bq = (const float*)d_in[2];
    const float* Wk = (const float*)d_in[3];
    const float* bk = (const float*)d_in[4];
    const float* Wv = (const float*)d_in[5];
    const float* bv = (const float*)d_in[6];
    const float* Wo = (const float*)d_in[7];
    const float* bo = (const float*)d_in[8];
    float* out = (float*)d_out;

    if (ws_size < (size_t)51 * 1024 * 1024) return;

    u16* ws  = (u16*)d_ws;
    u16* xb  = ws;                       // 4096*1024
    u16* wqt = xb  + 4096 * 1024;
    u16* wkt = wqt + 1024 * 1024;
    u16* wvt = wkt + 1024 * 1024;
    u16* wot = wvt + 1024 * 1024;
    u16* Qb  = wot + 1024 * 1024;        // [B,H,2048,64]
    u16* Kb  = Qb + 4194304;             // [B,H,2048,64]
    u16* Vtb = Kb + 4194304;             // [B,H,64,2048]  (transposed)
    u16* Ob  = Vtb + 4194304;            // [4096][1024]

    cast_x_kernel<<<4096, 256, 0, stream>>>((const float4*)x, xb);
    transpose_cast<<<1024, 256, 0, stream>>>(Wq, Wk, Wv, Wo, wqt, wkt, wvt, wot);
    gemm_kernel<0><<<768, 256, 0, stream>>>(xb, wqt, wkt, wvt, bq, bk, bv,
                                            Qb, Kb, Vtb, nullptr);
    attn_kernel<<<512, 256, 0, stream>>>(Qb, Kb, Vtb, Ob);
    gemm_kernel<1><<<256, 256, 0, stream>>>(Ob, wot, nullptr, nullptr, bo, nullptr, nullptr,
                                            nullptr, nullptr, nullptr, out);
}